// Round 1
// baseline (17.152 us; speedup 1.0000x reference)
//
#include <hip/hip_runtime.h>
#include <math.h>

// out[b,n,m,0:3] = min_delta ; [3] = min_dist ; [4] = min_dist2(clamped) ; [5] = min_dist_norm
__global__ void geom_kernel(const float* __restrict__ coords,
                            const float* __restrict__ lattice,
                            float* __restrict__ out,
                            int B, int N) {
    int idx = blockIdx.x * blockDim.x + threadIdx.x;
    int total = B * N * N;
    if (idx >= total) return;

    int m = idx % N;
    int n = (idx / N) % N;
    int b = idx / (N * N);

    // --- lattice -> Gram (fp32, mirroring jnp order) ---
    const float* lat = lattice + b * 6;
    float l0 = fminf(fmaxf(lat[0], -5.0f), 5.0f);
    float l1 = fminf(fmaxf(lat[1], -5.0f), 5.0f);
    float l2 = fminf(fmaxf(lat[2], -5.0f), 5.0f);
    float ca = fminf(fmaxf(lat[3], -0.9999f), 0.9999f);
    float cb = fminf(fmaxf(lat[4], -0.9999f), 0.9999f);
    float cg = fminf(fmaxf(lat[5], -0.9999f), 0.9999f);

    float a = expf(l0);
    float bl = expf(l1);
    float c = expf(l2);

    // jnp products are left-associative: (a*b)*cg etc.
    float G00 = a * a;
    float G01 = (a * bl) * cg;
    float G02 = (a * c) * cb;
    float G11 = bl * bl;
    float G12 = (bl * c) * ca;
    float G22 = c * c;

    // --- delta ---
    const float* cn = coords + ((size_t)b * N + n) * 3;
    const float* cm = coords + ((size_t)b * N + m) * 3;
    float dx = cn[0] - cm[0];
    float dy = cn[1] - cm[1];
    float dz = cn[2] - cm[2];

    // --- argmin over 27 images, first-occurrence semantics (strict <) ---
    float best = INFINITY;
    int bestk = 0;
    #pragma unroll
    for (int k = 0; k < 27; ++k) {
        float ox = (float)(k / 9) - 1.0f;
        float oy = (float)((k / 3) % 3) - 1.0f;
        float oz = (float)(k % 3) - 1.0f;
        float d0 = dx + ox;
        float d1 = dy + oy;
        float d2 = dz + oz;
        // einsum 'bnmki,bij,bnmkj': tmp_j = sum_i d_i G_ij ; dist2 = sum_j tmp_j d_j
        float t0 = d0 * G00 + d1 * G01 + d2 * G02;
        float t1 = d0 * G01 + d1 * G11 + d2 * G12;
        float t2 = d0 * G02 + d1 * G12 + d2 * G22;
        float dist2 = t0 * d0 + t1 * d1 + t2 * d2;
        if (dist2 < best) { best = dist2; bestk = k; }
    }

    float ox = (float)(bestk / 9) - 1.0f;
    float oy = (float)((bestk / 3) % 3) - 1.0f;
    float oz = (float)(bestk % 3) - 1.0f;
    float mdx = dx + ox;
    float mdy = dy + oy;
    float mdz = dz + oz;

    float md2 = fmaxf(best, 0.0f);
    bool pos = md2 > 0.0f;
    float mdist = pos ? sqrtf(md2) : 0.0f;

    // nan0 safety (inputs finite so normally no-ops, but keep exact semantics)
    if (!isfinite(mdist)) mdist = 0.0f;
    if (!isfinite(md2)) md2 = 0.0f;

    float mean_len = (a + bl + c) / 3.0f;   // jnp.mean over 3
    float cell = fmaxf(mean_len, 1e-6f);
    float mnorm = mdist / cell;
    if (!isfinite(mnorm)) mnorm = 0.0f;

    size_t base = (((size_t)b * N + n) * N + m) * 6;
    out[base + 0] = mdx;
    out[base + 1] = mdy;
    out[base + 2] = mdz;
    out[base + 3] = mdist;
    out[base + 4] = md2;
    out[base + 5] = mnorm;
}

extern "C" void kernel_launch(void* const* d_in, const int* in_sizes, int n_in,
                              void* d_out, int out_size, void* d_ws, size_t ws_size,
                              hipStream_t stream) {
    const float* coords = (const float*)d_in[0];   // (8, 320, 3) f32
    const float* lattice = (const float*)d_in[1];  // (8, 6) f32
    float* out = (float*)d_out;                    // (8, 320, 320, 6) f32

    const int B = 8;
    const int N = in_sizes[0] / (B * 3);           // 320
    int total = B * N * N;
    int block = 256;
    int grid = (total + block - 1) / block;
    geom_kernel<<<grid, block, 0, stream>>>(coords, lattice, out, B, N);
}

// Round 2
// 14.987 us; speedup vs baseline: 1.1445x; 1.1445x over previous
//
#include <hip/hip_runtime.h>
#include <math.h>

// out[b,n,m,0:3] = min_delta ; [3] = min_dist ; [4] = min_dist2(clamped) ; [5] = min_dist_norm
__global__ void __launch_bounds__(256) geom_kernel(const float* __restrict__ coords,
                                                   const float* __restrict__ lattice,
                                                   float* __restrict__ out,
                                                   int B, int N) {
    int idx = blockIdx.x * blockDim.x + threadIdx.x;
    int total = B * N * N;
    if (idx >= total) return;

    int m = idx % N;
    int n = (idx / N) % N;
    int b = idx / (N * N);

    // --- lattice -> Gram (fp32, mirroring jnp clip/exp/product order) ---
    const float* lat = lattice + b * 6;
    float l0 = fminf(fmaxf(lat[0], -5.0f), 5.0f);
    float l1 = fminf(fmaxf(lat[1], -5.0f), 5.0f);
    float l2 = fminf(fmaxf(lat[2], -5.0f), 5.0f);
    float ca = fminf(fmaxf(lat[3], -0.9999f), 0.9999f);
    float cb = fminf(fmaxf(lat[4], -0.9999f), 0.9999f);
    float cg = fminf(fmaxf(lat[5], -0.9999f), 0.9999f);

    float a  = expf(l0);
    float bl = expf(l1);
    float c  = expf(l2);

    float G00 = a * a;
    float G01 = (a * bl) * cg;
    float G02 = (a * c) * cb;
    float G11 = bl * bl;
    float G12 = (bl * c) * ca;
    float G22 = c * c;

    // hoisted doubled off-diagonals for the nested-Horner quadratic form
    float twoG01 = G01 + G01;
    float twoG02 = G02 + G02;
    float twoG12 = G12 + G12;

    // --- delta ---
    const float* cn = coords + ((size_t)b * N + n) * 3;
    const float* cm = coords + ((size_t)b * N + m) * 3;
    float dx = cn[0] - cm[0];
    float dy = cn[1] - cm[1];
    float dz = cn[2] - cm[2];

    // --- argmin over 27 images, first-occurrence semantics (strict <) ---
    // dist2 = G00 e0^2 + G11 e1^2 + G22 e2^2 + 2G01 e0 e1 + 2G02 e0 e2 + 2G12 e1 e2
    //       = u(e0) + e1*(G11 e1 + 2G01 e0) + e2*(G22 e2 + 2G12 e1 + 2G02 e0)
    // Quadratic symmetry Q(-x)==Q(x) holds bitwise, so diagonal (d=0) tie
    // semantics (first occurrence) remain exact under strict <.
    float best = INFINITY;
    int bestk = 0;
    #pragma unroll
    for (int kx = 0; kx < 3; ++kx) {
        float e0 = dx + (float)(kx - 1);
        float u   = (e0 * G00) * e0;
        float t01 = e0 * twoG01;
        float t02 = e0 * twoG02;
        #pragma unroll
        for (int ky = 0; ky < 3; ++ky) {
            float e1 = dy + (float)(ky - 1);
            float v = fmaf(e1, fmaf(e1, G11, t01), u);
            float w = fmaf(e1, twoG12, t02);
            #pragma unroll
            for (int kz = 0; kz < 3; ++kz) {
                float e2 = dz + (float)(kz - 1);
                float f = fmaf(e2, G22, w);
                float dist2 = fmaf(e2, f, v);
                int k = kx * 9 + ky * 3 + kz;
                if (dist2 < best) { best = dist2; bestk = k; }
            }
        }
    }

    float ox = (float)(bestk / 9) - 1.0f;
    float oy = (float)((bestk / 3) % 3) - 1.0f;
    float oz = (float)(bestk % 3) - 1.0f;
    float mdx = dx + ox;
    float mdy = dy + oy;
    float mdz = dz + oz;

    float md2 = fmaxf(best, 0.0f);
    bool pos = md2 > 0.0f;
    float mdist = pos ? sqrtf(md2) : 0.0f;

    if (!isfinite(mdist)) mdist = 0.0f;
    if (!isfinite(md2)) md2 = 0.0f;

    float mean_len = (a + bl + c) / 3.0f;
    float cell = fmaxf(mean_len, 1e-6f);
    float mnorm = mdist / cell;
    if (!isfinite(mnorm)) mnorm = 0.0f;

    size_t base = (((size_t)b * N + n) * N + m) * 6;
    out[base + 0] = mdx;
    out[base + 1] = mdy;
    out[base + 2] = mdz;
    out[base + 3] = mdist;
    out[base + 4] = md2;
    out[base + 5] = mnorm;
}

extern "C" void kernel_launch(void* const* d_in, const int* in_sizes, int n_in,
                              void* d_out, int out_size, void* d_ws, size_t ws_size,
                              hipStream_t stream) {
    const float* coords = (const float*)d_in[0];   // (8, 320, 3) f32
    const float* lattice = (const float*)d_in[1];  // (8, 6) f32
    float* out = (float*)d_out;                    // (8, 320, 320, 6) f32

    const int B = 8;
    const int N = in_sizes[0] / (B * 3);           // 320
    int total = B * N * N;
    int block = 256;
    int grid = (total + block - 1) / block;
    geom_kernel<<<grid, block, 0, stream>>>(coords, lattice, out, B, N);
}